// Round 5
// baseline (553.925 us; speedup 1.0000x reference)
//
#include <hip/hip_runtime.h>
#include <math.h>

// ---------------- Kernel Z: zero the whole output, memset-style ----------------
__global__ __launch_bounds__(256) void zero_out(float4* __restrict__ out4, int nf4,
                                                float* __restrict__ out, int out_size) {
    int gid = blockIdx.x * blockDim.x + threadIdx.x;
    int stride = gridDim.x * blockDim.x;
    const float4 z = make_float4(0.f, 0.f, 0.f, 0.f);
    for (int i = gid; i < nf4; i += stride) out4[i] = z;
    if (gid == 0) {                       // scalar tail (out_size % 4)
        for (int k = nf4 * 4; k < out_size; ++k) out[k] = 0.f;
    }
}

// ---------------- Kernel P: paint only each mask's box rectangle ----------------
__device__ __forceinline__ float bilin(const float* __restrict__ r0,
                                       const float* __restrict__ r1,
                                       float px, float vy0, float vy1, int Wm) {
    float fx = floorf(px);
    int ix = (int)fx;
    float wx1 = px - fx;
    float wx0 = 1.f - wx1;
    float vx0 = (ix >= 0 && ix < Wm) ? wx0 : 0.f;
    float vx1 = (ix + 1 >= 0 && ix + 1 < Wm) ? wx1 : 0.f;
    int rx0 = min(max(ix, 0), Wm - 1);
    int rx1 = min(max(ix + 1, 0), Wm - 1);
    float top = r0[rx0] * vx0 + r0[rx1] * vx1;
    float bot = r1[rx0] * vx0 + r1[rx1] * vx1;
    return top * vy0 + bot * vy1;
}

__global__ __launch_bounds__(128) void paint_box(const float* __restrict__ masks,
                       const float* __restrict__ boxes,
                       const int* __restrict__ p_img_h,
                       const int* __restrict__ p_img_w,
                       const int* __restrict__ p_in_h,
                       const int* __restrict__ p_in_w,
                       float* __restrict__ out,
                       int HW, int Hm, int Wm) {
    const int n = blockIdx.x;
    const int img_w = p_img_w[0];
    const int img_h = HW / img_w;

    float fw = (float)img_w, fh = (float)img_h;
    float sx = fw / (float)p_in_w[0];
    float sy = fh / (float)p_in_h[0];
    float x0 = fminf(fmaxf(boxes[4*n+0] * sx, 0.f), fw);
    float y0 = fminf(fmaxf(boxes[4*n+1] * sy, 0.f), fh);
    float x1 = fminf(fmaxf(boxes[4*n+2] * sx, 0.f), fw);
    float y1 = fminf(fmaxf(boxes[4*n+3] * sy, 0.f), fh);
    float swx = (float)Wm / (x1 - x0);
    float swy = (float)Hm / (y1 - y0);

    // Conservative pixel bounds of the nonzero support (bilin returns 0 on slack)
    int xlo = max(0,     (int)floorf(x0 - 0.5f / swx - 0.5f) - 1);
    int xhi = min(img_w, (int)ceilf (x0 + ((float)Wm + 0.5f) / swx - 0.5f) + 2);
    int ylo = max(0,     (int)floorf(y0 - 0.5f / swy - 0.5f) - 1);
    int yhi = min(img_h, (int)ceilf (y0 + ((float)Hm + 0.5f) / swy - 0.5f) + 2);

    const float* mb = masks + (size_t)n * Hm * Wm;
    float* ob = out + (size_t)n * HW;

    for (int y = ylo + blockIdx.y; y < yhi; y += gridDim.y) {
        float py = ((float)y + 0.5f - y0) * swy - 0.5f;
        float fy = floorf(py);
        int iy = (int)fy;
        float wy1 = py - fy, wy0 = 1.f - wy1;
        float vy0 = (iy >= 0 && iy < Hm) ? wy0 : 0.f;
        float vy1 = (iy + 1 >= 0 && iy + 1 < Hm) ? wy1 : 0.f;
        const float* r0 = mb + (size_t)min(max(iy, 0), Hm - 1) * Wm;
        const float* r1 = mb + (size_t)min(max(iy + 1, 0), Hm - 1) * Wm;
        float* orow = ob + (size_t)y * img_w;
        for (int x = xlo + (int)threadIdx.x; x < xhi; x += (int)blockDim.x) {
            float px = ((float)x + 0.5f - x0) * swx - 0.5f;
            orow[x] = bilin(r0, r1, px, vy0, vy1, Wm);
        }
    }
}

extern "C" void kernel_launch(void* const* d_in, const int* in_sizes, int n_in,
                              void* d_out, int out_size, void* d_ws, size_t ws_size,
                              hipStream_t stream) {
    const float* masks  = (const float*)d_in[0];
    const float* boxes  = (const float*)d_in[1];
    const int* p_img_h  = (const int*)d_in[2];
    const int* p_img_w  = (const int*)d_in[3];
    const int* p_in_h   = (const int*)d_in[4];
    const int* p_in_w   = (const int*)d_in[5];

    int N = in_sizes[1] / 4;                 // boxes = [N,4]
    int mask_hw = in_sizes[0] / N;           // Hm*Wm
    int Wm = (int)(sqrtf((float)mask_hw) + 0.5f);
    int Hm = mask_hw / Wm;
    int HW = out_size / N;                   // img_h * img_w

    // Phase 1: zero everything (memset-speed)
    int nf4 = out_size / 4;
    int zblocks = 4096;
    hipLaunchKernelGGL(zero_out, dim3(zblocks), dim3(256), 0, stream,
                       (float4*)d_out, nf4, (float*)d_out, out_size);

    // Phase 2: paint each mask's box region (runs after Z on the same stream)
    hipLaunchKernelGGL(paint_box, dim3(N, 512), dim3(128), 0, stream,
                       masks, boxes, p_img_h, p_img_w, p_in_h, p_in_w,
                       (float*)d_out, HW, Hm, Wm);
}

// Round 6
// 523.819 us; speedup vs baseline: 1.0575x; 1.0575x over previous
//
#include <hip/hip_runtime.h>
#include <math.h>

#define ROWTPB 320              // 320 threads * 4 px = 1280-px row per block

// params[n] = {x0, y0, swx = Wm/(x1-x0), swy = Hm/(y1-y0)}
__global__ __launch_bounds__(128) void setup_params(
        const float* __restrict__ boxes,
        const int* __restrict__ p_img_h, const int* __restrict__ p_img_w,
        const int* __restrict__ p_in_h,  const int* __restrict__ p_in_w,
        float4* __restrict__ params, int N, int Hm, int Wm) {
    int n = blockIdx.x * blockDim.x + threadIdx.x;
    if (n >= N) return;
    float fw = (float)p_img_w[0], fh = (float)p_img_h[0];
    float sx = fw / (float)p_in_w[0];
    float sy = fh / (float)p_in_h[0];
    float x0 = fminf(fmaxf(boxes[4*n+0] * sx, 0.f), fw);
    float y0 = fminf(fmaxf(boxes[4*n+1] * sy, 0.f), fh);
    float x1 = fminf(fmaxf(boxes[4*n+2] * sx, 0.f), fw);
    float y1 = fminf(fmaxf(boxes[4*n+3] * sy, 0.f), fh);
    params[n] = make_float4(x0, y0, (float)Wm / (x1 - x0), (float)Hm / (y1 - y0));
}

__device__ __forceinline__ float bilinx(const float* __restrict__ r0,
                                        const float* __restrict__ r1,
                                        float px, float vy0, float vy1, int Wm) {
    float fx = floorf(px);
    int ix = (int)fx;
    float wx1 = px - fx;
    float wx0 = 1.f - wx1;
    float vx0 = (ix >= 0 && ix < Wm) ? wx0 : 0.f;
    float vx1 = (ix + 1 >= 0 && ix + 1 < Wm) ? wx1 : 0.f;
    int rx0 = min(max(ix, 0), Wm - 1);
    int rx1 = min(max(ix + 1, 0), Wm - 1);
    return (r0[rx0] * vx0 + r0[rx1] * vx1) * vy0
         + (r1[rx0] * vx0 + r1[rx1] * vx1) * vy1;
}

__device__ __forceinline__ float sample_one(const float* __restrict__ mb,
                                            float px, float py, int Hm, int Wm) {
    if (py <= -1.f || py >= (float)Hm || px <= -1.f || px >= (float)Wm) return 0.f;
    float fy = floorf(py);
    int iy = (int)fy;
    float wy1 = py - fy, wy0 = 1.f - wy1;
    float vy0 = (iy >= 0) ? wy0 : 0.f;              // iy <= Hm-1 guaranteed by py < Hm
    float vy1 = (iy + 1 < Hm) ? wy1 : 0.f;          // iy+1 >= 0 guaranteed by py > -1
    const float* r0 = mb + (size_t)max(iy, 0) * Wm;
    const float* r1 = mb + (size_t)min(iy + 1, Hm - 1) * Wm;
    return bilinx(r0, r1, px, vy0, vy1, Wm);
}

__global__ __launch_bounds__(ROWTPB) void paste_rows(
        const float* __restrict__ masks,
        const float4* __restrict__ params,
        const int* __restrict__ p_img_w,
        float* __restrict__ out,
        int HW, int Hm, int Wm) {
    const int img_w = p_img_w[0];                    // uniform scalar load
    const int n = blockIdx.y;
    const float4 P = params[n];                      // uniform -> scalar regs
    const float* mb = masks + (size_t)n * Hm * Wm;
    float* ob = out + (size_t)n * HW;

    if (img_w == ROWTPB * 4) {
        // -------- fast path: one block == one image row, 4 px/thread --------
        const int y = blockIdx.x;
        const int x = (int)threadIdx.x * 4;
        float* op = ob + (size_t)y * img_w + x;

        float py = ((float)y + 0.5f - P.y) * P.w - 0.5f;   // uniform
        if (py <= -1.f || py >= (float)Hm) {               // uniform branch: zero row
            *(float4*)op = make_float4(0.f, 0.f, 0.f, 0.f);
            return;
        }
        float fy = floorf(py);
        int iy = (int)fy;                                  // in [-1, Hm-1]
        float wy1 = py - fy, wy0 = 1.f - wy1;
        float vy0 = (iy >= 0) ? wy0 : 0.f;
        float vy1 = (iy + 1 < Hm) ? wy1 : 0.f;
        const float* r0 = mb + (size_t)max(iy, 0) * Wm;
        const float* r1 = mb + (size_t)min(iy + 1, Hm - 1) * Wm;

        float px0 = ((float)x + 0.5f - P.x) * P.z - 0.5f;
        float px3 = px0 + 3.f * P.z;                       // P.z > 0
        if (px3 <= -1.f || px0 >= (float)Wm) {             // whole quad outside
            *(float4*)op = make_float4(0.f, 0.f, 0.f, 0.f);
            return;
        }
        float4 r;
        r.x = bilinx(r0, r1, px0,            vy0, vy1, Wm);
        r.y = bilinx(r0, r1, px0 +      P.z, vy0, vy1, Wm);
        r.z = bilinx(r0, r1, px0 + 2.f* P.z, vy0, vy1, Wm);
        r.w = bilinx(r0, r1, px3,            vy0, vy1, Wm);
        *(float4*)op = r;
    } else {
        // -------- generic fallback (any img_w): grid-stride, scalar stores --------
        int tid = blockIdx.x * ROWTPB + threadIdx.x;
        int nthreads = gridDim.x * ROWTPB;
        for (int base = tid * 4; base < HW; base += nthreads * 4) {
            for (int i = 0; i < 4 && base + i < HW; ++i) {
                int idx = base + i;
                int y = idx / img_w;
                int x = idx - y * img_w;
                float py = ((float)y + 0.5f - P.y) * P.w - 0.5f;
                float px = ((float)x + 0.5f - P.x) * P.z - 0.5f;
                ob[idx] = sample_one(mb, px, py, Hm, Wm);
            }
        }
    }
}

extern "C" void kernel_launch(void* const* d_in, const int* in_sizes, int n_in,
                              void* d_out, int out_size, void* d_ws, size_t ws_size,
                              hipStream_t stream) {
    const float* masks  = (const float*)d_in[0];
    const float* boxes  = (const float*)d_in[1];
    const int* p_img_h  = (const int*)d_in[2];
    const int* p_img_w  = (const int*)d_in[3];
    const int* p_in_h   = (const int*)d_in[4];
    const int* p_in_w   = (const int*)d_in[5];

    int N = in_sizes[1] / 4;                 // boxes = [N,4]
    int mask_hw = in_sizes[0] / N;           // Hm*Wm
    int Wm = (int)(sqrtf((float)mask_hw) + 0.5f);
    int Hm = mask_hw / Wm;
    int HW = out_size / N;                   // img_h * img_w

    float4* params = (float4*)d_ws;

    hipLaunchKernelGGL(setup_params, dim3((N + 127) / 128), dim3(128), 0, stream,
                       boxes, p_img_h, p_img_w, p_in_h, p_in_w, params, N, Hm, Wm);

    // rows when img_w == 1280; fallback grid-strides so any shape is covered
    int rows = HW / (ROWTPB * 4);
    if (rows < 1) rows = 1;
    dim3 grid(rows, N);
    hipLaunchKernelGGL(paste_rows, grid, dim3(ROWTPB), 0, stream,
                       masks, params, p_img_w, (float*)d_out, HW, Hm, Wm);
}